// Round 6
// baseline (159.515 us; speedup 1.0000x reference)
//
#include <hip/hip_runtime.h>
#include <hip/hip_bf16.h>

#define NDIM 16
#define HDIM 128
#define BATCH 256
#define EPS_D 1e-6f

typedef float v2f __attribute__((ext_vector_type(2)));
static __device__ __forceinline__ v2f v2(float a, float b) {
  v2f r; r.x = a; r.y = b; return r;
}
static __device__ __forceinline__ v2f splat(float a) {
  v2f r; r.x = a; r.y = a; return r;
}
// Guaranteed packed-fp32 math (VOP3P). gfx950 fp32 peak (157.3 TF) is only
// reachable via v_pk_*_f32, so these must assemble.
static __device__ __forceinline__ v2f pk_fma(v2f a, v2f b, v2f c) {
  v2f d;
  asm("v_pk_fma_f32 %0, %1, %2, %3" : "=v"(d) : "v"(a), "v"(b), "v"(c));
  return d;
}
static __device__ __forceinline__ v2f pk_mul(v2f a, v2f b) {
  v2f d;
  asm("v_pk_mul_f32 %0, %1, %2" : "=v"(d) : "v"(a), "v"(b));
  return d;
}
static __device__ __forceinline__ v2f pk_add(v2f a, v2f b) {
  v2f d;
  asm("v_pk_add_f32 %0, %1, %2" : "=v"(d) : "v"(a), "v"(b));
  return d;
}

// Eigen/XNNPACK fast tanh rational approximation coefficients.
#define TCLAMP 7.99881172180175781f
#define CA1 4.89352455891786e-03f
#define CA3 6.37261928875436e-04f
#define CA5 1.48572235717979e-05f
#define CA7 5.12229709037114e-08f
#define CA9 -8.60467152213735e-11f
#define CA11 2.00018790482477e-13f
#define CA13 -2.76076847742355e-16f
#define CB0 4.89352518554385e-03f
#define CB2 2.26843463243900e-03f
#define CB4 1.18534705686654e-04f
#define CB6 1.19825839466702e-06f

// ---- Kernel 1: metric = sym(MLP(points)) + eps*I, rW1 block projections,
//      and zero-init of the G accumulator.
__global__ __launch_bounds__(256) void metric_proj_kernel(
    const float* __restrict__ points,
    const float* __restrict__ mW1, const float* __restrict__ mb1,
    const float* __restrict__ mW2, const float* __restrict__ mb2,
    const float* __restrict__ rW1, const float* __restrict__ rb1,
    float* __restrict__ metric,
    float* __restrict__ A1, float* __restrict__ Mi, float* __restrict__ Mj,
    float* __restrict__ G) {
  int b = blockIdx.x;
  int t = threadIdx.x;  // 0..255
  __shared__ float p[16];
  __shared__ float mh[128];
  __shared__ float raw[256];
  __shared__ float M[256];
  G[b * 256 + t] = 0.f;
  if (t < 16) p[t] = points[b * 16 + t];
  __syncthreads();
  if (t < 128) {
    float acc = mb1[t];
#pragma unroll
    for (int k = 0; k < 16; ++k) acc = fmaf(p[k], mW1[k * 128 + t], acc);
    mh[t] = fmaxf(acc, 0.f);
  }
  __syncthreads();
  {
    float acc = mb2[t];
#pragma unroll 8
    for (int h = 0; h < 128; ++h) acc = fmaf(mh[h], mW2[h * 256 + t], acc);
    raw[t] = acc;
  }
  __syncthreads();
  {
    int i = t >> 4, j = t & 15;
    float v = 0.5f * (raw[i * 16 + j] + raw[j * 16 + i]);
    if (i == j) v += EPS_D;
    M[t] = v;
    metric[b * 256 + t] = v;
  }
  __syncthreads();
  {
    int h = t;
    float wB[16], wC[16];
#pragma unroll
    for (int c = 0; c < 16; ++c) {
      wB[c] = rW1[(16 + c) * 256 + h];
      wC[c] = rW1[(32 + c) * 256 + h];
    }
    float a = rb1[h];
#pragma unroll
    for (int r = 0; r < 16; ++r) a = fmaf(p[r], rW1[r * 256 + h], a);
    A1[b * 256 + h] = a;
#pragma unroll 2
    for (int i = 0; i < 16; ++i) {
      float mi = 0.f, mj = 0.f;
#pragma unroll
      for (int c = 0; c < 16; ++c) {
        float m = M[i * 16 + c];
        mi = fmaf(m, wB[c], mi);
        mj = fmaf(m, wC[c], mj);
      }
      Mi[(b * 16 + i) * 256 + h] = mi;
      Mj[(b * 16 + i) * 256 + h] = mj;
    }
  }
}

// ---- Kernel 2: fused christoffel MLP + ricci layer-1 relu + i-reduction ----
// One 128-thread block (2 waves) per (b,i). Phase 1: each wave covers ALL 256
// triples (4 per lane, jk = l + 64m, same k across m) for HALF the hidden
// range (wave w: h in [64w, 64w+64)); partial sums combined in LDS.
// tanh = Eigen rational x*P(x^2)/Q(x^2), clamp via v_med3; the four
// Q-reciprocals per lane-step share ONE v_rcp_f32:
//   pAB=qA*qB; r=rcp(pAB.x*pAB.y); u2=(r*pAB.y, r*pAB.x);
//   invA=u2*qB; invB=u2*qA.   (plain pk_muls, short chain)
// All math is guaranteed v_pk_*_f32 via inline asm; weights are stored
// duplicated in LDS so every operand is a ready VGPR pair.
__global__ __launch_bounds__(128, 6) void chr_kernel(
    const float* __restrict__ metric,
    const float* __restrict__ cW1, const float* __restrict__ cb1,
    const float* __restrict__ cW2, const float* __restrict__ cb2,
    const float* __restrict__ rW1,
    const float* __restrict__ A1, const float* __restrict__ Mi,
    const float* __restrict__ Mj,
    float* __restrict__ G) {
  int bi = blockIdx.x;         // b*16 + i
  int b = bi >> 4, i = bi & 15;
  int t = threadIdx.x;         // 0..127
  int w = t >> 6, l = t & 63;  // wave, lane
  __shared__ float M[256];
  __shared__ float4 zAB[128];   // {w0,w0,w1,w1} per h
  __shared__ float4 zCD[128];   // {w2b,w2b,b1,b1} per h
  __shared__ float2 zE[128];    // {w2out,w2out} per h
  __shared__ float chpart[512]; // 2 waves x 256 partials
  __shared__ float2 chd[256];   // combined christoffel, duplicated pairs
  M[t] = metric[b * 256 + t];
  M[t + 128] = metric[b * 256 + t + 128];
  {
    float w0 = cW1[t], w1 = cW1[128 + t], w2b = cW1[256 + t];
    float b1v = cb1[t], w2o = cW2[t];
    zAB[t] = make_float4(w0, w0, w1, w1);
    zCD[t] = make_float4(w2b, w2b, b1v, b1v);
    zE[t] = make_float2(w2o, w2o);
  }
  __syncthreads();

  // ---- phase 1: 4 triples/lane (jk = l+64m), h in [64w, 64w+64) ----
  {
    int j0 = l >> 4, k0 = l & 15;
    v2f x0A = v2(M[i * 16 + j0], M[i * 16 + j0 + 4]);
    v2f x0B = v2(M[i * 16 + j0 + 8], M[i * 16 + j0 + 12]);
    v2f x1A = v2(M[l], M[l + 64]);        // M[j0*16+k0] identities
    v2f x1B = v2(M[l + 128], M[l + 192]);
    v2f x2p = splat(M[k0 * 16 + i]);
    v2f accA = (w == 0) ? splat(cb2[0]) : splat(0.f);
    v2f accB = accA;
    const v2f kA13 = splat(CA13), kA11 = splat(CA11), kA9 = splat(CA9);
    const v2f kA7 = splat(CA7), kA5 = splat(CA5), kA3 = splat(CA3);
    const v2f kA1 = splat(CA1);
    const v2f kB6 = splat(CB6), kB4 = splat(CB4), kB2 = splat(CB2);
    const v2f kB0 = splat(CB0);
#pragma unroll 2
    for (int hh = 0; hh < 64; ++hh) {
      int h = (w << 6) + hh;
      float4 ZA = zAB[h];
      float4 ZC = zCD[h];
      float2 ZE = zE[h];
      v2f w0p = v2(ZA.x, ZA.y), w1p = v2(ZA.z, ZA.w);
      v2f w2bp = v2(ZC.x, ZC.y), b1p = v2(ZC.z, ZC.w);
      v2f w2p = v2(ZE.x, ZE.y);
      v2f bb = pk_fma(x2p, w2bp, b1p);
      v2f tA = pk_fma(x0A, w0p, pk_fma(x1A, w1p, bb));
      v2f tB = pk_fma(x0B, w0p, pk_fma(x1B, w1p, bb));
      tA.x = __builtin_amdgcn_fmed3f(tA.x, -TCLAMP, TCLAMP);
      tA.y = __builtin_amdgcn_fmed3f(tA.y, -TCLAMP, TCLAMP);
      tB.x = __builtin_amdgcn_fmed3f(tB.x, -TCLAMP, TCLAMP);
      tB.y = __builtin_amdgcn_fmed3f(tB.y, -TCLAMP, TCLAMP);
      v2f sA = pk_mul(tA, tA), sB = pk_mul(tB, tB);
      v2f pA = pk_fma(sA, kA13, kA11), pB = pk_fma(sB, kA13, kA11);
      pA = pk_fma(pA, sA, kA9);  pB = pk_fma(pB, sB, kA9);
      pA = pk_fma(pA, sA, kA7);  pB = pk_fma(pB, sB, kA7);
      pA = pk_fma(pA, sA, kA5);  pB = pk_fma(pB, sB, kA5);
      pA = pk_fma(pA, sA, kA3);  pB = pk_fma(pB, sB, kA3);
      pA = pk_fma(pA, sA, kA1);  pB = pk_fma(pB, sB, kA1);
      pA = pk_mul(pA, tA);       pB = pk_mul(pB, tB);
      v2f qA = pk_fma(sA, kB6, kB4), qB = pk_fma(sB, kB6, kB4);
      qA = pk_fma(qA, sA, kB2);  qB = pk_fma(qB, sB, kB2);
      qA = pk_fma(qA, sA, kB0);  qB = pk_fma(qB, sB, kB0);
      // one reciprocal for all four q's (q >= CB0 > 0)
      v2f pAB = pk_mul(qA, qB);
      float r = __builtin_amdgcn_rcpf(pAB.x * pAB.y);
      v2f u2 = v2(r * pAB.y, r * pAB.x);  // (1/pAB.x, 1/pAB.y)
      v2f invA = pk_mul(u2, qB);          // (1/qA.x, 1/qA.y)
      v2f invB = pk_mul(u2, qA);
      v2f thA = pk_mul(pA, invA), thB = pk_mul(pB, invB);
      accA = pk_fma(thA, w2p, accA);
      accB = pk_fma(thB, w2p, accB);
    }
    chpart[w * 256 + l] = accA.x;
    chpart[w * 256 + l + 64] = accA.y;
    chpart[w * 256 + l + 128] = accB.x;
    chpart[w * 256 + l + 192] = accB.y;
  }
  __syncthreads();
  {
    float s0 = chpart[t] + chpart[256 + t];
    float s1 = chpart[t + 128] + chpart[256 + t + 128];
    chd[t] = make_float2(s0, s0);
    chd[t + 128] = make_float2(s1, s1);
  }
  __syncthreads();

  // ---- phase 2: hidden-unit pair (t, t+128) per thread ----
  {
    int h0 = t, h1 = t + 128;
    v2f rc2[16];
#pragma unroll
    for (int kk = 0; kk < 16; ++kk) {
      const float* row = rW1 + (48 + kk) * 256;
      rc2[kk] = v2(row[h0], row[h1]);
    }
    const float* A1b = A1 + b * 256;
    const float* Mib = Mi + bi * 256;
    v2f base = v2(A1b[h0] + Mib[h0], A1b[h1] + Mib[h1]);
    v2f hacc = splat(0.f);
    for (int jj = 0; jj < 16; ++jj) {
      const float* Mjr = Mj + (b * 16 + jj) * 256;
      v2f cp = pk_add(base, v2(Mjr[h0], Mjr[h1]));
#pragma unroll
      for (int kk = 0; kk < 16; ++kk) {
        float2 c = chd[jj * 16 + kk];
        cp = pk_fma(v2(c.x, c.y), rc2[kk], cp);
      }
      cp.x = fmaxf(cp.x, 0.f);
      cp.y = fmaxf(cp.y, 0.f);
      hacc = pk_add(hacc, cp);
    }
    atomicAdd(&G[b * 256 + h0], hacc.x);
    atomicAdd(&G[b * 256 + h1], hacc.y);
  }
}

// ---- Kernel 3: linear layer 2 on G, symmetrize, scale ----------------------
__global__ __launch_bounds__(256) void final_kernel(
    const float* __restrict__ G,
    const float* __restrict__ rW2, const float* __restrict__ rb2,
    float* __restrict__ out) {
  int b = blockIdx.x;
  int t = threadIdx.x;
  __shared__ float4 Gs[64];
  __shared__ float T[256];
  if (t < 64) Gs[t] = ((const float4*)(G + b * 256))[t];
  __syncthreads();
  float acc = 256.f * rb2[t];
#pragma unroll 4
  for (int h4 = 0; h4 < 64; ++h4) {
    float4 gg = Gs[h4];
    acc = fmaf(gg.x, rW2[(h4 * 4 + 0) * 256 + t], acc);
    acc = fmaf(gg.y, rW2[(h4 * 4 + 1) * 256 + t], acc);
    acc = fmaf(gg.z, rW2[(h4 * 4 + 2) * 256 + t], acc);
    acc = fmaf(gg.w, rW2[(h4 * 4 + 3) * 256 + t], acc);
  }
  T[t] = acc * (1.f / 256.f);
  __syncthreads();
  int k = t >> 4, lcol = t & 15;
  out[b * 256 + t] = 0.5f * (T[k * 16 + lcol] + T[lcol * 16 + k]);
}

extern "C" void kernel_launch(void* const* d_in, const int* in_sizes, int n_in,
                              void* d_out, int out_size, void* d_ws, size_t ws_size,
                              hipStream_t stream) {
  const float* points = (const float*)d_in[0];
  const float* mW1 = (const float*)d_in[1];
  const float* mb1 = (const float*)d_in[2];
  const float* mW2 = (const float*)d_in[3];
  const float* mb2 = (const float*)d_in[4];
  const float* cW1 = (const float*)d_in[5];
  const float* cb1 = (const float*)d_in[6];
  const float* cW2 = (const float*)d_in[7];
  const float* cb2 = (const float*)d_in[8];
  const float* rW1 = (const float*)d_in[9];
  const float* rb1 = (const float*)d_in[10];
  const float* rW2 = (const float*)d_in[11];
  const float* rb2 = (const float*)d_in[12];
  float* out = (float*)d_out;

  float* ws = (float*)d_ws;
  float* metric = ws;                 // 65536
  float* A1 = metric + 65536;         // 65536
  float* Mi = A1 + 65536;             // 1048576
  float* Mj = Mi + 1048576;           // 1048576
  float* G = Mj + 1048576;            // 65536

  metric_proj_kernel<<<BATCH, 256, 0, stream>>>(points, mW1, mb1, mW2, mb2,
                                                rW1, rb1, metric, A1, Mi, Mj, G);
  chr_kernel<<<BATCH * NDIM, 128, 0, stream>>>(metric, cW1, cb1, cW2, cb2, rW1,
                                               A1, Mi, Mj, G);
  final_kernel<<<BATCH, 256, 0, stream>>>(G, rW2, rb2, out);
}

// Round 7
// 137.679 us; speedup vs baseline: 1.1586x; 1.1586x over previous
//
#include <hip/hip_runtime.h>
#include <hip/hip_bf16.h>
#include <math.h>

#define NDIM 16
#define HDIM 128
#define BATCH 256
#define EPS_D 1e-6f

// ---- Kernel 1: metric = sym(MLP(points)) + eps*I, rW1 block projections,
//      G zero-init, and the PWL tanh table build (512 segments on [-8,8]).
__global__ __launch_bounds__(256) void metric_proj_kernel(
    const float* __restrict__ points,
    const float* __restrict__ mW1, const float* __restrict__ mb1,
    const float* __restrict__ mW2, const float* __restrict__ mb2,
    const float* __restrict__ rW1, const float* __restrict__ rb1,
    float* __restrict__ metric,
    float* __restrict__ A1, float* __restrict__ Mi, float* __restrict__ Mj,
    float* __restrict__ G, float* __restrict__ tanhtab) {
  int b = blockIdx.x;
  int t = threadIdx.x;  // 0..255
  __shared__ float p[16];
  __shared__ float mh[128];
  __shared__ float raw[256];
  __shared__ float M[256];
  G[b * 256 + t] = 0.f;
  // ---- tanh PWL table: entries t and t+256 (all blocks write same values)
  {
    int e = t;
#pragma unroll
    for (int m = 0; m < 2; ++m) {
      float x0 = (e - 256) * 0.03125f;
      float y0 = tanhf(x0);
      float y1 = tanhf(x0 + 0.03125f);
      float slope = (y1 - y0) * 32.f;
      tanhtab[e * 2] = slope;
      tanhtab[e * 2 + 1] = fmaf(-slope, x0, y0);
      e += 256;
    }
  }
  if (t < 16) p[t] = points[b * 16 + t];
  __syncthreads();
  if (t < 128) {
    float acc = mb1[t];
#pragma unroll
    for (int k = 0; k < 16; ++k) acc = fmaf(p[k], mW1[k * 128 + t], acc);
    mh[t] = fmaxf(acc, 0.f);
  }
  __syncthreads();
  {
    float acc = mb2[t];
#pragma unroll 8
    for (int h = 0; h < 128; ++h) acc = fmaf(mh[h], mW2[h * 256 + t], acc);
    raw[t] = acc;
  }
  __syncthreads();
  {
    int i = t >> 4, j = t & 15;
    float v = 0.5f * (raw[i * 16 + j] + raw[j * 16 + i]);
    if (i == j) v += EPS_D;
    M[t] = v;
    metric[b * 256 + t] = v;
  }
  __syncthreads();
  {
    int h = t;
    float wB[16], wC[16];
#pragma unroll
    for (int c = 0; c < 16; ++c) {
      wB[c] = rW1[(16 + c) * 256 + h];
      wC[c] = rW1[(32 + c) * 256 + h];
    }
    float a = rb1[h];
#pragma unroll
    for (int r = 0; r < 16; ++r) a = fmaf(p[r], rW1[r * 256 + h], a);
    A1[b * 256 + h] = a;
#pragma unroll 2
    for (int i = 0; i < 16; ++i) {
      float mi = 0.f, mj = 0.f;
#pragma unroll
      for (int c = 0; c < 16; ++c) {
        float m = M[i * 16 + c];
        mi = fmaf(m, wB[c], mi);
        mj = fmaf(m, wC[c], mj);
      }
      Mi[(b * 16 + i) * 256 + h] = mi;
      Mj[(b * 16 + i) * 256 + h] = mj;
    }
  }
}

// ---- Kernel 2: fused christoffel MLP + ricci layer-1 relu + i-reduction ----
// One 128-thread block (2 waves) per (b,i). Phase 1: lane l of wave w owns
// triples jk = 128w+l and 128w+l+64 (same k, j differs by 4); the tanh is a
// 512-segment piecewise-linear LDS table lookup (NO transcendentals):
//   idx = clamp((int)(x*32+256), 0, 511); th = fma(slope[idx], x, icpt[idx])
// Phase 2 (after barrier): hidden-unit pair (t, t+128) per thread.
__global__ __launch_bounds__(128, 8) void chr_kernel(
    const float* __restrict__ metric,
    const float* __restrict__ cW1, const float* __restrict__ cb1,
    const float* __restrict__ cW2, const float* __restrict__ cb2,
    const float* __restrict__ rW1,
    const float* __restrict__ A1, const float* __restrict__ Mi,
    const float* __restrict__ Mj,
    const float* __restrict__ tanhtab,
    float* __restrict__ G) {
  int bi = blockIdx.x;         // b*16 + i
  int b = bi >> 4, i = bi & 15;
  int t = threadIdx.x;         // 0..127
  int w = t >> 6, l = t & 63;  // wave, lane
  __shared__ float M[256];
  __shared__ float4 z[128];    // {w1_0h, w1_1h, w1_2h, b1h}
  __shared__ float w2s[128];
  __shared__ float2 tab[512];  // {slope, icpt} per segment
  __shared__ float chf[256];
  M[t] = metric[b * 256 + t];
  M[t + 128] = metric[b * 256 + t + 128];
  if (t < 128) {
    z[t] = make_float4(cW1[t], cW1[128 + t], cW1[256 + t], cb1[t]);
    w2s[t] = cW2[t];
  }
  {
    const float4* tg = (const float4*)tanhtab;
    float4* tl = (float4*)tab;
    tl[t] = tg[t];
    tl[t + 128] = tg[t + 128];
  }
  __syncthreads();

  // ---- phase 1: triples jk0 = 128w+l, jk1 = jk0+64 ----
  {
    int jk0 = w * 128 + l;
    int j0 = jk0 >> 4, k0 = jk0 & 15;
    float x00 = M[i * 16 + j0], x01 = M[i * 16 + j0 + 4];
    float x10 = M[j0 * 16 + k0], x11 = M[(j0 + 4) * 16 + k0];
    float x2s = M[k0 * 16 + i];
    float acc0 = 0.f, acc1 = 0.f;
    float c2 = cb2[0];
#pragma unroll 4
    for (int h = 0; h < 128; ++h) {
      float4 Q = z[h];
      float wh = w2s[h];
      float bb = fmaf(x2s, Q.z, Q.w);
      float p0 = fmaf(x00, Q.x, fmaf(x10, Q.y, bb));
      float p1 = fmaf(x01, Q.x, fmaf(x11, Q.y, bb));
      int i0 = (int)fmaf(p0, 32.f, 256.f);
      int i1 = (int)fmaf(p1, 32.f, 256.f);
      i0 = min(max(i0, 0), 511);
      i1 = min(max(i1, 0), 511);
      float2 s0 = tab[i0];
      float2 s1 = tab[i1];
      acc0 = fmaf(wh, fmaf(s0.x, p0, s0.y), acc0);
      acc1 = fmaf(wh, fmaf(s1.x, p1, s1.y), acc1);
    }
    chf[jk0] = acc0 + c2;
    chf[jk0 + 64] = acc1 + c2;
  }
  __syncthreads();  // phase 2 reads BOTH waves' ch values

  // ---- phase 2: hidden-unit pair (t, t+128) per thread ----
  {
    int h0 = t, h1 = t + 128;
    float rc0[16], rc1[16];
#pragma unroll
    for (int kk = 0; kk < 16; ++kk) {
      const float* row = rW1 + (48 + kk) * 256;
      rc0[kk] = row[h0];
      rc1[kk] = row[h1];
    }
    const float* A1b = A1 + b * 256;
    const float* Mib = Mi + bi * 256;
    float base0 = A1b[h0] + Mib[h0];
    float base1 = A1b[h1] + Mib[h1];
    float hacc0 = 0.f, hacc1 = 0.f;
    const float4* ch4 = (const float4*)chf;
    for (int jj = 0; jj < 16; ++jj) {
      float4 c0 = ch4[jj * 4 + 0];
      float4 c1 = ch4[jj * 4 + 1];
      float4 c2v = ch4[jj * 4 + 2];
      float4 c3 = ch4[jj * 4 + 3];
      float cc[16] = {c0.x, c0.y, c0.z, c0.w, c1.x, c1.y, c1.z, c1.w,
                      c2v.x, c2v.y, c2v.z, c2v.w, c3.x, c3.y, c3.z, c3.w};
      const float* Mjr = Mj + (b * 16 + jj) * 256;
      float cp0 = base0 + Mjr[h0];
      float cp1 = base1 + Mjr[h1];
#pragma unroll
      for (int kk = 0; kk < 16; ++kk) {
        cp0 = fmaf(cc[kk], rc0[kk], cp0);
        cp1 = fmaf(cc[kk], rc1[kk], cp1);
      }
      hacc0 += fmaxf(cp0, 0.f);
      hacc1 += fmaxf(cp1, 0.f);
    }
    atomicAdd(&G[b * 256 + h0], hacc0);
    atomicAdd(&G[b * 256 + h1], hacc1);
  }
}

// ---- Kernel 3: linear layer 2 on G, symmetrize, scale ----------------------
__global__ __launch_bounds__(256) void final_kernel(
    const float* __restrict__ G,
    const float* __restrict__ rW2, const float* __restrict__ rb2,
    float* __restrict__ out) {
  int b = blockIdx.x;
  int t = threadIdx.x;
  __shared__ float4 Gs[64];
  __shared__ float T[256];
  if (t < 64) Gs[t] = ((const float4*)(G + b * 256))[t];
  __syncthreads();
  float acc = 256.f * rb2[t];
#pragma unroll 4
  for (int h4 = 0; h4 < 64; ++h4) {
    float4 gg = Gs[h4];
    acc = fmaf(gg.x, rW2[(h4 * 4 + 0) * 256 + t], acc);
    acc = fmaf(gg.y, rW2[(h4 * 4 + 1) * 256 + t], acc);
    acc = fmaf(gg.z, rW2[(h4 * 4 + 2) * 256 + t], acc);
    acc = fmaf(gg.w, rW2[(h4 * 4 + 3) * 256 + t], acc);
  }
  T[t] = acc * (1.f / 256.f);
  __syncthreads();
  int k = t >> 4, lcol = t & 15;
  out[b * 256 + t] = 0.5f * (T[k * 16 + lcol] + T[lcol * 16 + k]);
}

extern "C" void kernel_launch(void* const* d_in, const int* in_sizes, int n_in,
                              void* d_out, int out_size, void* d_ws, size_t ws_size,
                              hipStream_t stream) {
  const float* points = (const float*)d_in[0];
  const float* mW1 = (const float*)d_in[1];
  const float* mb1 = (const float*)d_in[2];
  const float* mW2 = (const float*)d_in[3];
  const float* mb2 = (const float*)d_in[4];
  const float* cW1 = (const float*)d_in[5];
  const float* cb1 = (const float*)d_in[6];
  const float* cW2 = (const float*)d_in[7];
  const float* cb2 = (const float*)d_in[8];
  const float* rW1 = (const float*)d_in[9];
  const float* rb1 = (const float*)d_in[10];
  const float* rW2 = (const float*)d_in[11];
  const float* rb2 = (const float*)d_in[12];
  float* out = (float*)d_out;

  float* ws = (float*)d_ws;
  float* metric = ws;                 // 65536
  float* A1 = metric + 65536;         // 65536
  float* Mi = A1 + 65536;             // 1048576
  float* Mj = Mi + 1048576;           // 1048576
  float* G = Mj + 1048576;            // 65536
  float* tanhtab = G + 65536;         // 1024 (512 x {slope, icpt})

  metric_proj_kernel<<<BATCH, 256, 0, stream>>>(points, mW1, mb1, mW2, mb2,
                                                rW1, rb1, metric, A1, Mi, Mj,
                                                G, tanhtab);
  chr_kernel<<<BATCH * NDIM, 128, 0, stream>>>(metric, cW1, cb1, cW2, cb2, rW1,
                                               A1, Mi, Mj, tanhtab, G);
  final_kernel<<<BATCH, 256, 0, stream>>>(G, rW2, rb2, out);
}